// Round 12
// baseline (129.446 us; speedup 1.0000x reference)
//
#include <hip/hip_runtime.h>
#include <hip/hip_bf16.h>
#include <cstdint>

// Problem constants (features: [512, 16, 512] fp32 -> N=8192 rows, D=512)
#define N_TOT 8192
#define DDIM  512
#define DBYTES 512                     // bytes per row in fp8
#define NBLK  64                       // 8192 / 128 tile blocks per dim
#define NTRI  (NBLK * (NBLK + 1) / 2)  // 2080 lower-triangle blocks
constexpr float INV_T = 1.0f / 0.07f;

typedef uint8_t u8;
typedef __attribute__((ext_vector_type(8))) int i32x8_t;
typedef __attribute__((ext_vector_type(4))) float f32x4_t;

// ---- helpers ---------------------------------------------------------------

// async 16B global->LDS (global_load_lds_dwordx4). LDS dst is wave-uniform
// base + lane*16 (lane-contiguous) -- swizzle is applied to the GLOBAL src.
__device__ __forceinline__ void load16_to_lds(const void* g, void* l) {
  __builtin_amdgcn_global_load_lds(
      (const __attribute__((address_space(1))) unsigned int*)g,
      (__attribute__((address_space(3))) unsigned int*)l, 16, 0, 0);
}

// ---- kernel 1: row-normalize fp32 -> fp8 e4m3 (+ zero tsum, counter, out) --
__global__ __launch_bounds__(256) void normalize_kernel(const float* __restrict__ X,
                                                        u8* __restrict__ Xn,
                                                        float* __restrict__ tsum,
                                                        float* __restrict__ out) {
  if (blockIdx.x < 32) tsum[blockIdx.x * 256 + threadIdx.x] = 0.0f;
  if (blockIdx.x == 32 && threadIdx.x == 0) {
    ((unsigned int*)(tsum + N_TOT))[0] = 0u;  // done-counter
    out[0] = 0.0f;
  }
  const int lane = threadIdx.x & 63;
  const int row  = blockIdx.x * 4 + (threadIdx.x >> 6);
  const float4* xr = (const float4*)(X + (size_t)row * DDIM);
  float4 v0 = xr[lane];
  float4 v1 = xr[lane + 64];
  float s = v0.x * v0.x + v0.y * v0.y + v0.z * v0.z + v0.w * v0.w
          + v1.x * v1.x + v1.y * v1.y + v1.z * v1.z + v1.w * v1.w;
#pragma unroll
  for (int m = 1; m < 64; m <<= 1) s += __shfl_xor(s, m);
  const float scale = 1.0f / fmaxf(sqrtf(s), 1e-8f);
  int w0 = __builtin_amdgcn_cvt_pk_fp8_f32(v0.x * scale, v0.y * scale, 0, 0);
  w0     = __builtin_amdgcn_cvt_pk_fp8_f32(v0.z * scale, v0.w * scale, w0, 1);
  int w1 = __builtin_amdgcn_cvt_pk_fp8_f32(v1.x * scale, v1.y * scale, 0, 0);
  w1     = __builtin_amdgcn_cvt_pk_fp8_f32(v1.z * scale, v1.w * scale, w1, 1);
  uint32_t* orow = (uint32_t*)(Xn + (size_t)row * DBYTES);
  orow[lane]      = (uint32_t)w0;
  orow[lane + 64] = (uint32_t)w1;
}

// ---- kernel 2: lower-triangle tiles of C = Xn*Xn^T, fused exp row/col sums,
//                FENCE-FREE last-block finalize --------------------------------
// GEMM body is exactly R7 (best measured: 56 us): fp8 128x128 tile, BK=128
// (4 K-iters), 256 threads = 4 waves in 2x2, mfma_scale 16x16x128 f8f6f4
// (e4m3, unit E8M0 scales), single-buffered 32 KB LDS, (256,3).
// Finalize protocol (R3 lesson: NO __threadfence / NO ACQ_REL -- those emit
// buffer_inv = per-XCD L2 invalidate -> 3x regression): tsum writes are
// device-scope atomics (coherent at L2); __syncthreads() drains each wave's
// vmcnt before the barrier, so afterwards all this block's atomics are
// globally visible; then one RELAXED fetch_add on the done-counter (no cache
// maintenance emitted); last block reads tsum via RELAXED agent atomic loads
// (L1-bypass, no invalidate) and writes out[0].
// LDS XOR swizzle (R2-verified conflict-free frag reads): granule (row, j)
// j=0..7 (16B) stored at slot row*8 + (j ^ (row&7)); global src inverts it.
__global__ __launch_bounds__(256, 3) void gemm_exp_rowsum(const u8* __restrict__ Xn,
                                                          float* __restrict__ tsum,
                                                          float* __restrict__ out) {
  __shared__ __align__(16) u8 sA[128 * 128];  // 16 KB
  __shared__ __align__(16) u8 sB[128 * 128];  // 16 KB

  // triangular decode: blockIdx.x -> (bi >= bj)
  const int k = blockIdx.x;
  int bi = (int)((sqrtf(8.0f * (float)k + 1.0f) - 1.0f) * 0.5f);
  while ((bi + 1) * (bi + 2) / 2 <= k) ++bi;
  while (bi * (bi + 1) / 2 > k) --bi;
  const int bj = k - bi * (bi + 1) / 2;
  const int rowBase = bi * 128;
  const int colBase = bj * 128;
  const bool isDiag = (bi == bj);

  const int t    = threadIdx.x;   // 0..255
  const int lane = t & 63;
  const int l15  = lane & 15;
  const int quad = lane >> 4;
  const int w    = t >> 6;        // 0..3
  const int wm   = w >> 1;        // 0..1: row offset wm*64
  const int wn   = w & 1;         // 0..1: col offset wn*64

  f32x4_t acc[4][4];
#pragma unroll
  for (int i = 0; i < 4; i++)
#pragma unroll
    for (int j = 0; j < 4; j++) acc[i][j] = {0.f, 0.f, 0.f, 0.f};

  // staging map: per panel 1024 granules of 16B (128 rows x 8); thread t
  // handles granules t, t+256, t+512, t+768 -> rows srow+{0,32,64,96} at the
  // same swizzle-inverted byte offset goff ((srow+32)&7 == srow&7).
  const int srow = t >> 3;
  const int goff = ((t & 7) ^ (srow & 7)) * 16;
  const u8* gA = Xn + (size_t)(rowBase + srow) * DBYTES + goff;
  const u8* gB = Xn + (size_t)(colBase + srow) * DBYTES + goff;
  u8* lA = sA + t * 16;
  u8* lB = sB + t * 16;

  for (int k0 = 0; k0 < DBYTES; k0 += 128) {  // 4 iters
#pragma unroll
    for (int r = 0; r < 4; r++) {
      load16_to_lds(gA + (size_t)(r * 32) * DBYTES + k0, lA + r * 4096);
      load16_to_lds(gB + (size_t)(r * 32) * DBYTES + k0, lB + r * 4096);
    }
    __syncthreads();

    i32x8_t a[4], b[4];
#pragma unroll
    for (int mi = 0; mi < 4; mi++) {
      const int row = wm * 64 + mi * 16 + l15;
      const int s0 = (((quad * 2) ^ (row & 7)) * 16);
      const int s1 = (((quad * 2 + 1) ^ (row & 7)) * 16);
      int4 lo = *(const int4*)&sA[row * 128 + s0];
      int4 hi = *(const int4*)&sA[row * 128 + s1];
      a[mi] = (i32x8_t){lo.x, lo.y, lo.z, lo.w, hi.x, hi.y, hi.z, hi.w};
    }
#pragma unroll
    for (int ni = 0; ni < 4; ni++) {
      const int row = wn * 64 + ni * 16 + l15;
      const int s0 = (((quad * 2) ^ (row & 7)) * 16);
      const int s1 = (((quad * 2 + 1) ^ (row & 7)) * 16);
      int4 lo = *(const int4*)&sB[row * 128 + s0];
      int4 hi = *(const int4*)&sB[row * 128 + s1];
      b[ni] = (i32x8_t){lo.x, lo.y, lo.z, lo.w, hi.x, hi.y, hi.z, hi.w};
    }

#pragma unroll
    for (int mi = 0; mi < 4; mi++)
#pragma unroll
      for (int ni = 0; ni < 4; ni++)
        acc[mi][ni] = __builtin_amdgcn_mfma_scale_f32_16x16x128_f8f6f4(
            a[mi], b[ni], acc[mi][ni], 0, 0, 0, 0x7F7F7F7Fu, 0, 0x7F7F7F7Fu);
    __syncthreads();
  }

  // epilogue: e = exp((c-1)/T). C/D layout: col = lane&15, row = quad*4 + reg
  // (shape-determined, dtype-independent -- m121..m128).
  if (isDiag) {
#pragma unroll
    for (int mi = 0; mi < 4; mi++) {
#pragma unroll
      for (int r = 0; r < 4; r++) {
        const int row = rowBase + wm * 64 + mi * 16 + quad * 4 + r;
        float rs = 0.0f;
#pragma unroll
        for (int ni = 0; ni < 4; ni++) {
          const int col = colBase + wn * 64 + ni * 16 + l15;
          const float e = __expf((acc[mi][ni][r] - 1.0f) * INV_T);
          rs += (row == col) ? 0.0f : e;
        }
        rs += __shfl_xor(rs, 1);
        rs += __shfl_xor(rs, 2);
        rs += __shfl_xor(rs, 4);
        rs += __shfl_xor(rs, 8);
        if (l15 == 0) atomicAdd(&tsum[row], rs);
      }
    }
  } else {
    float csum[4] = {0.f, 0.f, 0.f, 0.f};
#pragma unroll
    for (int mi = 0; mi < 4; mi++) {
#pragma unroll
      for (int r = 0; r < 4; r++) {
        const int row = rowBase + wm * 64 + mi * 16 + quad * 4 + r;
        float rs = 0.0f;
#pragma unroll
        for (int ni = 0; ni < 4; ni++) {
          const float e = __expf((acc[mi][ni][r] - 1.0f) * INV_T);
          rs += e;
          csum[ni] += e;
        }
        rs += __shfl_xor(rs, 1);
        rs += __shfl_xor(rs, 2);
        rs += __shfl_xor(rs, 4);
        rs += __shfl_xor(rs, 8);
        if (l15 == 0) atomicAdd(&tsum[row], rs);
      }
    }
#pragma unroll
    for (int ni = 0; ni < 4; ni++) {
      csum[ni] += __shfl_xor(csum[ni], 16);
      csum[ni] += __shfl_xor(csum[ni], 32);
      if (quad == 0) atomicAdd(&tsum[colBase + wn * 64 + ni * 16 + l15], csum[ni]);
    }
  }

  // ---- fence-free last-block finalize --------------------------------------
  __shared__ bool isLast;
  // each wave drains its own vmcnt before the barrier -> after it, ALL of
  // this block's tsum atomics are at the L2 coherence point. No cache ops.
  __syncthreads();
  if (t == 0) {
    unsigned int* cnt = (unsigned int*)(tsum + N_TOT);
    unsigned int prev = __hip_atomic_fetch_add(cnt, 1u, __ATOMIC_RELAXED,
                                               __HIP_MEMORY_SCOPE_AGENT);
    isLast = (prev == NTRI - 1);
  }
  __syncthreads();
  if (isLast) {
    float s = 0.0f;
    for (int i = t; i < N_TOT; i += 256) {
      // relaxed agent atomic load: L1-bypassing read at the coherence point
      float v = __hip_atomic_load(&tsum[i], __ATOMIC_RELAXED,
                                  __HIP_MEMORY_SCOPE_AGENT);
      s += log1pf(v);
    }
#pragma unroll
    for (int m = 1; m < 64; m <<= 1) s += __shfl_xor(s, m);
    __shared__ float ws[4];
    if ((t & 63) == 0) ws[t >> 6] = s;
    __syncthreads();
    if (t == 0) out[0] = (ws[0] + ws[1] + ws[2] + ws[3]) * (1.0f / N_TOT);
  }
}

// ---- launcher --------------------------------------------------------------
extern "C" void kernel_launch(void* const* d_in, const int* in_sizes, int n_in,
                              void* d_out, int out_size, void* d_ws, size_t ws_size,
                              hipStream_t stream) {
  const float* X = (const float*)d_in[0];
  float* out = (float*)d_out;

  float* tsum = (float*)d_ws;                       // 8192 fp32 + counter
  u8* Xn = (u8*)d_ws + 65536;                       // 8192x512 fp8 = 4 MB

  normalize_kernel<<<N_TOT / 4, 256, 0, stream>>>(X, Xn, tsum, out);
  gemm_exp_rowsum<<<NTRI, 256, 0, stream>>>(Xn, tsum, out);
}